// Round 1
// baseline (6104.543 us; speedup 1.0000x reference)
//
#include <hip/hip_runtime.h>
#include <cstdint>
#include <cstddef>

// ---------------------------------------------------------------------------
// CCA-SSG forward: 2-layer GraphConv (norm='both') x 2 graphs + column z-score
// Round 1: f32 everywhere; SpMM via float atomics (CSR planned for round 2).
// ---------------------------------------------------------------------------

// ---- degree computation (both graphs in one pass) -------------------------
__global__ void degree_kernel(const int* __restrict__ src1, const int* __restrict__ dst1,
                              const int* __restrict__ src2, const int* __restrict__ dst2,
                              int* __restrict__ do1, int* __restrict__ di1,
                              int* __restrict__ do2, int* __restrict__ di2, int E)
{
    int t = blockIdx.x * blockDim.x + threadIdx.x;
    if (t >= E) return;
    atomicAdd(&do1[src1[t]], 1);
    atomicAdd(&di1[dst1[t]], 1);
    atomicAdd(&do2[src2[t]], 1);
    atomicAdd(&di2[dst2[t]], 1);
}

// ---- fused elementwise + GEMM: Y[r][c] = sum_k f(X[r][k]) * W[k][c] -------
// FUSE=false: f(x) = x * rsqrt(max(deg_out,1))            (layer 1 from feat)
// FUSE=true : f(x) = relu(x*rsqrt(max(deg_in,1))+b1[k]) * rsqrt(max(deg_out,1))
// Tile: 32 rows x 128 cols per block (256 threads), 4x4 register blocking.
__global__ __launch_bounds__(256) void gemm128_pre(
    const float* __restrict__ X, const float* __restrict__ W,
    const int* __restrict__ deg_out, const int* __restrict__ deg_in,
    const float* __restrict__ bias, float* __restrict__ Y, int M, int fuse)
{
    __shared__ float xs[32][129];   // +1 pad: conflict-free staging stores
    const int tid  = threadIdx.x;
    const int row0 = blockIdx.x * 32;

    // stage 32x128 input tile with the elementwise transform fused in
#pragma unroll
    for (int i = 0; i < 16; ++i) {
        int idx = tid + i * 256;
        int r = idx >> 7, c = idx & 127;
        int gr = row0 + r;
        float v = 0.f;
        if (gr < M) {
            v = X[(size_t)gr * 128 + c];
            if (fuse) {
                float si = rsqrtf(fmaxf((float)deg_in[gr], 1.f));
                v = fmaxf(v * si + bias[c], 0.f);
            }
            float so = rsqrtf(fmaxf((float)deg_out[gr], 1.f));
            v *= so;
        }
        xs[r][c] = v;
    }
    __syncthreads();

    const int r4 = (tid >> 5) * 4;       // 8 row-groups
    const int cg = (tid & 31);           // 32 col-groups (4 cols each)
    float acc[4][4] = {};
    const float4* Wv = (const float4*)W; // [128][32] float4, row-major

#pragma unroll 4
    for (int k = 0; k < 128; ++k) {
        float4 w = Wv[k * 32 + cg];
        float x0 = xs[r4 + 0][k];
        float x1 = xs[r4 + 1][k];
        float x2 = xs[r4 + 2][k];
        float x3 = xs[r4 + 3][k];
        acc[0][0] = fmaf(x0, w.x, acc[0][0]); acc[0][1] = fmaf(x0, w.y, acc[0][1]);
        acc[0][2] = fmaf(x0, w.z, acc[0][2]); acc[0][3] = fmaf(x0, w.w, acc[0][3]);
        acc[1][0] = fmaf(x1, w.x, acc[1][0]); acc[1][1] = fmaf(x1, w.y, acc[1][1]);
        acc[1][2] = fmaf(x1, w.z, acc[1][2]); acc[1][3] = fmaf(x1, w.w, acc[1][3]);
        acc[2][0] = fmaf(x2, w.x, acc[2][0]); acc[2][1] = fmaf(x2, w.y, acc[2][1]);
        acc[2][2] = fmaf(x2, w.z, acc[2][2]); acc[2][3] = fmaf(x2, w.w, acc[2][3]);
        acc[3][0] = fmaf(x3, w.x, acc[3][0]); acc[3][1] = fmaf(x3, w.y, acc[3][1]);
        acc[3][2] = fmaf(x3, w.z, acc[3][2]); acc[3][3] = fmaf(x3, w.w, acc[3][3]);
    }

#pragma unroll
    for (int i = 0; i < 4; ++i) {
        int gr = row0 + r4 + i;
        if (gr < M) {
            float4 o = make_float4(acc[i][0], acc[i][1], acc[i][2], acc[i][3]);
            *(float4*)(Y + (size_t)gr * 128 + cg * 4) = o;
        }
    }
}

// ---- SpMM scatter: agg[dst[e]][:] += Y[src[e]][:] -------------------------
// 32 lanes per edge; float4 gather; 4 scalar f32 atomics per lane.
__global__ __launch_bounds__(256) void scatter_kernel(
    const float* __restrict__ Y, const int* __restrict__ src,
    const int* __restrict__ dst, float* __restrict__ agg, int E)
{
    int t = blockIdx.x * blockDim.x + threadIdx.x;
    int e = t >> 5, lane = t & 31;
    if (e >= E) return;
    int s = src[e], d = dst[e];
    float4 v = ((const float4*)(Y + (size_t)s * 128))[lane];
    float* out = agg + (size_t)d * 128 + lane * 4;
    atomicAdd(out + 0, v.x);
    atomicAdd(out + 1, v.y);
    atomicAdd(out + 2, v.z);
    atomicAdd(out + 3, v.w);
}

// ---- finalize layer 2 + column sum/sumsq ----------------------------------
// h = agg*rsqrt(max(deg_in,1)) + b2 ; write to Z; accumulate column stats.
__global__ __launch_bounds__(256) void finalize_stats(
    const float* __restrict__ AGG, const int* __restrict__ deg_in,
    const float* __restrict__ bias, float* __restrict__ Z,
    double* __restrict__ gsum, double* __restrict__ gsumsq, int M)
{
    const int c  = threadIdx.x & 127;
    const int rh = threadIdx.x >> 7;  // 0 or 1
    const float b = bias[c];
    float s = 0.f, s2 = 0.f;
    for (int row = blockIdx.x * 2 + rh; row < M; row += gridDim.x * 2) {
        float si = rsqrtf(fmaxf((float)deg_in[row], 1.f));
        float h = AGG[(size_t)row * 128 + c] * si + b;
        Z[(size_t)row * 128 + c] = h;
        s += h;
        s2 += h * h;
    }
    __shared__ float ls[256], ls2[256];
    ls[threadIdx.x] = s;
    ls2[threadIdx.x] = s2;
    __syncthreads();
    if (threadIdx.x < 128) {
        atomicAdd(&gsum[c],   (double)(ls[c] + ls[c + 128]));
        atomicAdd(&gsumsq[c], (double)(ls2[c] + ls2[c + 128]));
    }
}

// ---- mean / inv-std (ddof=1) ----------------------------------------------
__global__ void meanstd_kernel(const double* __restrict__ gsum,
                               const double* __restrict__ gsumsq, int M,
                               float* __restrict__ mean, float* __restrict__ istd)
{
    int c = threadIdx.x;
    double mu  = gsum[c] / (double)M;
    double var = (gsumsq[c] - gsum[c] * mu) / (double)(M - 1);
    mean[c] = (float)mu;
    istd[c] = (float)(1.0 / sqrt(var));
}

// ---- z-score in place -----------------------------------------------------
__global__ __launch_bounds__(256) void normalize_kernel(
    float* __restrict__ Z, const float* __restrict__ mean,
    const float* __restrict__ istd, int n4)
{
    int i = blockIdx.x * blockDim.x + threadIdx.x;
    if (i >= n4) return;
    float4 v = ((float4*)Z)[i];
    int c4 = (i & 31) << 2;   // 32 float4 per 128-wide row
    v.x = (v.x - mean[c4 + 0]) * istd[c4 + 0];
    v.y = (v.y - mean[c4 + 1]) * istd[c4 + 1];
    v.z = (v.z - mean[c4 + 2]) * istd[c4 + 2];
    v.w = (v.w - mean[c4 + 3]) * istd[c4 + 3];
    ((float4*)Z)[i] = v;
}

// ---------------------------------------------------------------------------
extern "C" void kernel_launch(void* const* d_in, const int* in_sizes, int n_in,
                              void* d_out, int out_size, void* d_ws, size_t ws_size,
                              hipStream_t stream)
{
    const float* feat1 = (const float*)d_in[0];
    const float* feat2 = (const float*)d_in[1];
    const float* W1    = (const float*)d_in[2];
    const float* b1    = (const float*)d_in[3];
    const float* W2    = (const float*)d_in[4];
    const float* b2    = (const float*)d_in[5];
    const int*   src1  = (const int*)d_in[6];
    const int*   dst1  = (const int*)d_in[7];
    const int*   src2  = (const int*)d_in[8];
    const int*   dst2  = (const int*)d_in[9];
    float* out = (float*)d_out;

    const int M = in_sizes[0] / 128;   // 100000 nodes
    const int E = in_sizes[6];         // 800000 edges

    // workspace carve-up
    float*  Y    = (float*)d_ws;                       // M*128 f32
    float*  AGG  = Y + (size_t)M * 128;                // M*128 f32
    int*    deg  = (int*)(AGG + (size_t)M * 128);      // 4*M int
    double* gsum = (double*)(deg + (size_t)4 * M);     // 128 f64
    double* gsq  = gsum + 128;                         // 128 f64
    float*  mean = (float*)(gsq + 128);                // 128 f32
    float*  istd = mean + 128;                         // 128 f32

    int* do1 = deg;
    int* di1 = deg + M;
    int* do2 = deg + 2 * M;
    int* di2 = deg + 3 * M;

    const int BLK = 256;
    const int gemm_blocks = (M + 31) / 32;
    const int scat_blocks = (E * 32 + BLK - 1) / BLK;
    const size_t mat_bytes = (size_t)M * 128 * sizeof(float);

    // degrees (both graphs)
    hipMemsetAsync(deg, 0, (size_t)4 * M * sizeof(int), stream);
    degree_kernel<<<(E + BLK - 1) / BLK, BLK, 0, stream>>>(
        src1, dst1, src2, dst2, do1, di1, do2, di2, E);

    for (int g = 0; g < 2; ++g) {
        const float* feat = g == 0 ? feat1 : feat2;
        const int* src = g == 0 ? src1 : src2;
        const int* dst = g == 0 ? dst1 : dst2;
        const int* dgo = g == 0 ? do1 : do2;
        const int* dgi = g == 0 ? di1 : di2;
        float* Zg = out + (size_t)g * M * 128;

        // layer 1: Y = (feat * rs_out) @ W1
        gemm128_pre<<<gemm_blocks, BLK, 0, stream>>>(feat, W1, dgo, nullptr, nullptr, Y, M, 0);
        hipMemsetAsync(AGG, 0, mat_bytes, stream);
        scatter_kernel<<<scat_blocks, BLK, 0, stream>>>(Y, src, dst, AGG, E);

        // layer 2: Y = (relu(agg*rs_in + b1) * rs_out) @ W2
        gemm128_pre<<<gemm_blocks, BLK, 0, stream>>>(AGG, W2, dgo, dgi, b1, Y, M, 1);
        hipMemsetAsync(AGG, 0, mat_bytes, stream);
        scatter_kernel<<<scat_blocks, BLK, 0, stream>>>(Y, src, dst, AGG, E);

        // finalize + z-score
        hipMemsetAsync(gsum, 0, 2 * 128 * sizeof(double), stream);
        finalize_stats<<<512, BLK, 0, stream>>>(AGG, dgi, b2, Zg, gsum, gsq, M);
        meanstd_kernel<<<1, 128, 0, stream>>>(gsum, gsq, M, mean, istd);
        normalize_kernel<<<(M * 32 + BLK - 1) / BLK, BLK, 0, stream>>>(Zg, mean, istd, M * 32);
    }
}

// Round 2
// 1028.798 us; speedup vs baseline: 5.9337x; 5.9337x over previous
//
#include <hip/hip_runtime.h>
#include <cstdint>
#include <cstddef>

// ---------------------------------------------------------------------------
// CCA-SSG forward: 2-layer GraphConv (norm='both') x 2 graphs + column z-score
// Round 2: replace atomic scatter SpMM (409.6M f32 atomics, 5.4ms) with
// on-the-fly CSR-by-dst build + register-accumulating gather SpMM (0 payload
// atomics). f32 everywhere.
// ---------------------------------------------------------------------------

#define SCAN_CHUNK 1024   // elements per scan block (256 thr x 4)

// ---- degree computation (both graphs in one pass) -------------------------
__global__ void degree_kernel(const int* __restrict__ src1, const int* __restrict__ dst1,
                              const int* __restrict__ src2, const int* __restrict__ dst2,
                              int* __restrict__ do1, int* __restrict__ di1,
                              int* __restrict__ do2, int* __restrict__ di2, int E)
{
    int t = blockIdx.x * blockDim.x + threadIdx.x;
    if (t >= E) return;
    atomicAdd(&do1[src1[t]], 1);
    atomicAdd(&di1[dst1[t]], 1);
    atomicAdd(&do2[src2[t]], 1);
    atomicAdd(&di2[dst2[t]], 1);
}

// ---- hierarchical exclusive scan of deg -> rowptr -------------------------
__global__ void scan_block_sums(const int* __restrict__ deg, int* __restrict__ partials, int M)
{
    __shared__ int sd[256];
    int base = blockIdx.x * SCAN_CHUNK + threadIdx.x * 4;
    int s = 0;
#pragma unroll
    for (int j = 0; j < 4; ++j) { int i = base + j; if (i < M) s += deg[i]; }
    sd[threadIdx.x] = s;
    __syncthreads();
    for (int off = 128; off > 0; off >>= 1) {
        if (threadIdx.x < off) sd[threadIdx.x] += sd[threadIdx.x + off];
        __syncthreads();
    }
    if (threadIdx.x == 0) partials[blockIdx.x] = sd[0];
}

__global__ void scan_partials(const int* __restrict__ partials, int* __restrict__ blockoff, int P)
{
    __shared__ int sd[256];
    int v = threadIdx.x < P ? partials[threadIdx.x] : 0;
    sd[threadIdx.x] = v;
    __syncthreads();
    for (int off = 1; off < 256; off <<= 1) {
        int t = threadIdx.x >= off ? sd[threadIdx.x - off] : 0;
        __syncthreads();
        sd[threadIdx.x] += t;
        __syncthreads();
    }
    if (threadIdx.x < P) blockoff[threadIdx.x] = sd[threadIdx.x] - v;  // exclusive
}

__global__ void scan_write(const int* __restrict__ deg, const int* __restrict__ blockoff,
                           int* __restrict__ rowptr, int M)
{
    __shared__ int sd[256];
    int base = blockIdx.x * SCAN_CHUNK + threadIdx.x * 4;
    int d0 = 0, d1 = 0, d2 = 0, d3 = 0;
    if (base + 0 < M) d0 = deg[base + 0];
    if (base + 1 < M) d1 = deg[base + 1];
    if (base + 2 < M) d2 = deg[base + 2];
    if (base + 3 < M) d3 = deg[base + 3];
    int tot = d0 + d1 + d2 + d3;
    sd[threadIdx.x] = tot;
    __syncthreads();
    for (int off = 1; off < 256; off <<= 1) {
        int t = threadIdx.x >= off ? sd[threadIdx.x - off] : 0;
        __syncthreads();
        sd[threadIdx.x] += t;
        __syncthreads();
    }
    int texcl = sd[threadIdx.x] - tot + blockoff[blockIdx.x];
    int p0 = texcl + d0, p1 = p0 + d1, p2 = p1 + d2, p3 = p2 + d3;
    if (base + 0 < M) rowptr[base + 1] = p0;
    if (base + 1 < M) rowptr[base + 2] = p1;
    if (base + 2 < M) rowptr[base + 3] = p2;
    if (base + 3 < M) rowptr[base + 4] = p3;
    if (blockIdx.x == 0 && threadIdx.x == 0) rowptr[0] = 0;
}

__global__ void copy_int(const int* __restrict__ a, int* __restrict__ b, int n)
{
    int i = blockIdx.x * blockDim.x + threadIdx.x;
    if (i < n) b[i] = a[i];
}

// ---- CSR fill: 800k int atomics (vs 409.6M f32 atomics before) ------------
__global__ void csr_fill(const int* __restrict__ src, const int* __restrict__ dst,
                         int* __restrict__ cursor, int* __restrict__ colidx, int E)
{
    int e = blockIdx.x * blockDim.x + threadIdx.x;
    if (e >= E) return;
    int pos = atomicAdd(&cursor[dst[e]], 1);
    colidx[pos] = src[e];
}

// ---- fused elementwise + GEMM: Y[r][c] = sum_k f(X[r][k]) * W[k][c] -------
__global__ __launch_bounds__(256) void gemm128_pre(
    const float* __restrict__ X, const float* __restrict__ W,
    const int* __restrict__ deg_out, const int* __restrict__ deg_in,
    const float* __restrict__ bias, float* __restrict__ Y, int M, int fuse)
{
    __shared__ float xs[32][129];
    const int tid  = threadIdx.x;
    const int row0 = blockIdx.x * 32;

#pragma unroll
    for (int i = 0; i < 16; ++i) {
        int idx = tid + i * 256;
        int r = idx >> 7, c = idx & 127;
        int gr = row0 + r;
        float v = 0.f;
        if (gr < M) {
            v = X[(size_t)gr * 128 + c];
            if (fuse) {
                float si = rsqrtf(fmaxf((float)deg_in[gr], 1.f));
                v = fmaxf(v * si + bias[c], 0.f);
            }
            float so = rsqrtf(fmaxf((float)deg_out[gr], 1.f));
            v *= so;
        }
        xs[r][c] = v;
    }
    __syncthreads();

    const int r4 = (tid >> 5) * 4;
    const int cg = (tid & 31);
    float acc[4][4] = {};
    const float4* Wv = (const float4*)W;

#pragma unroll 4
    for (int k = 0; k < 128; ++k) {
        float4 w = Wv[k * 32 + cg];
        float x0 = xs[r4 + 0][k];
        float x1 = xs[r4 + 1][k];
        float x2 = xs[r4 + 2][k];
        float x3 = xs[r4 + 3][k];
        acc[0][0] = fmaf(x0, w.x, acc[0][0]); acc[0][1] = fmaf(x0, w.y, acc[0][1]);
        acc[0][2] = fmaf(x0, w.z, acc[0][2]); acc[0][3] = fmaf(x0, w.w, acc[0][3]);
        acc[1][0] = fmaf(x1, w.x, acc[1][0]); acc[1][1] = fmaf(x1, w.y, acc[1][1]);
        acc[1][2] = fmaf(x1, w.z, acc[1][2]); acc[1][3] = fmaf(x1, w.w, acc[1][3]);
        acc[2][0] = fmaf(x2, w.x, acc[2][0]); acc[2][1] = fmaf(x2, w.y, acc[2][1]);
        acc[2][2] = fmaf(x2, w.z, acc[2][2]); acc[2][3] = fmaf(x2, w.w, acc[2][3]);
        acc[3][0] = fmaf(x3, w.x, acc[3][0]); acc[3][1] = fmaf(x3, w.y, acc[3][1]);
        acc[3][2] = fmaf(x3, w.z, acc[3][2]); acc[3][3] = fmaf(x3, w.w, acc[3][3]);
    }

#pragma unroll
    for (int i = 0; i < 4; ++i) {
        int gr = row0 + r4 + i;
        if (gr < M) {
            float4 o = make_float4(acc[i][0], acc[i][1], acc[i][2], acc[i][3]);
            *(float4*)(Y + (size_t)gr * 128 + cg * 4) = o;
        }
    }
}

// ---- gather SpMM: AGG[d][:] = sum_{e in row d} Y[col[e]][:] ---------------
// 32 lanes per node, one float4 per lane, register accumulation, no atomics.
__global__ __launch_bounds__(256) void gather_spmm(
    const float4* __restrict__ Yv, const int* __restrict__ rowptr,
    const int* __restrict__ colidx, float4* __restrict__ AGGv, int M)
{
    int t = blockIdx.x * blockDim.x + threadIdx.x;
    int node = t >> 5, lane = t & 31;
    if (node >= M) return;
    int e   = rowptr[node];
    int end = rowptr[node + 1];
    float ax = 0.f, ay = 0.f, az = 0.f, aw = 0.f;
    for (; e + 4 <= end; e += 4) {
        int s0 = colidx[e], s1 = colidx[e + 1], s2 = colidx[e + 2], s3 = colidx[e + 3];
        float4 v0 = Yv[(size_t)s0 * 32 + lane];
        float4 v1 = Yv[(size_t)s1 * 32 + lane];
        float4 v2 = Yv[(size_t)s2 * 32 + lane];
        float4 v3 = Yv[(size_t)s3 * 32 + lane];
        ax += v0.x + v1.x + v2.x + v3.x;
        ay += v0.y + v1.y + v2.y + v3.y;
        az += v0.z + v1.z + v2.z + v3.z;
        aw += v0.w + v1.w + v2.w + v3.w;
    }
    for (; e < end; ++e) {
        int s = colidx[e];
        float4 v = Yv[(size_t)s * 32 + lane];
        ax += v.x; ay += v.y; az += v.z; aw += v.w;
    }
    AGGv[(size_t)node * 32 + lane] = make_float4(ax, ay, az, aw);
}

// ---- finalize layer 2 + column sum/sumsq ----------------------------------
__global__ __launch_bounds__(256) void finalize_stats(
    const float* __restrict__ AGG, const int* __restrict__ deg_in,
    const float* __restrict__ bias, float* __restrict__ Z,
    double* __restrict__ gsum, double* __restrict__ gsumsq, int M)
{
    const int c  = threadIdx.x & 127;
    const int rh = threadIdx.x >> 7;
    const float b = bias[c];
    float s = 0.f, s2 = 0.f;
    for (int row = blockIdx.x * 2 + rh; row < M; row += gridDim.x * 2) {
        float si = rsqrtf(fmaxf((float)deg_in[row], 1.f));
        float h = AGG[(size_t)row * 128 + c] * si + b;
        Z[(size_t)row * 128 + c] = h;
        s += h;
        s2 += h * h;
    }
    __shared__ float ls[256], ls2[256];
    ls[threadIdx.x] = s;
    ls2[threadIdx.x] = s2;
    __syncthreads();
    if (threadIdx.x < 128) {
        atomicAdd(&gsum[c],   (double)(ls[c] + ls[c + 128]));
        atomicAdd(&gsumsq[c], (double)(ls2[c] + ls2[c + 128]));
    }
}

__global__ void meanstd_kernel(const double* __restrict__ gsum,
                               const double* __restrict__ gsumsq, int M,
                               float* __restrict__ mean, float* __restrict__ istd)
{
    int c = threadIdx.x;
    double mu  = gsum[c] / (double)M;
    double var = (gsumsq[c] - gsum[c] * mu) / (double)(M - 1);
    mean[c] = (float)mu;
    istd[c] = (float)(1.0 / sqrt(var));
}

__global__ __launch_bounds__(256) void normalize_kernel(
    float* __restrict__ Z, const float* __restrict__ mean,
    const float* __restrict__ istd, int n4)
{
    int i = blockIdx.x * blockDim.x + threadIdx.x;
    if (i >= n4) return;
    float4 v = ((float4*)Z)[i];
    int c4 = (i & 31) << 2;
    v.x = (v.x - mean[c4 + 0]) * istd[c4 + 0];
    v.y = (v.y - mean[c4 + 1]) * istd[c4 + 1];
    v.z = (v.z - mean[c4 + 2]) * istd[c4 + 2];
    v.w = (v.w - mean[c4 + 3]) * istd[c4 + 3];
    ((float4*)Z)[i] = v;
}

// ---------------------------------------------------------------------------
extern "C" void kernel_launch(void* const* d_in, const int* in_sizes, int n_in,
                              void* d_out, int out_size, void* d_ws, size_t ws_size,
                              hipStream_t stream)
{
    const float* feat1 = (const float*)d_in[0];
    const float* feat2 = (const float*)d_in[1];
    const float* W1    = (const float*)d_in[2];
    const float* b1    = (const float*)d_in[3];
    const float* W2    = (const float*)d_in[4];
    const float* b2    = (const float*)d_in[5];
    const int*   src1  = (const int*)d_in[6];
    const int*   dst1  = (const int*)d_in[7];
    const int*   src2  = (const int*)d_in[8];
    const int*   dst2  = (const int*)d_in[9];
    float* out = (float*)d_out;

    const int M = in_sizes[0] / 128;   // 100000
    const int E = in_sizes[6];         // 800000

    // workspace carve-up (doubles first after the big f32 matrices for alignment)
    float*  Y    = (float*)d_ws;                       // M*128 f32
    float*  AGG  = Y + (size_t)M * 128;                // M*128 f32
    double* gsum = (double*)(AGG + (size_t)M * 128);   // 128 f64
    double* gsq  = gsum + 128;                         // 128 f64
    float*  mean = (float*)(gsq + 128);                // 128 f32
    float*  istd = mean + 128;                         // 128 f32
    int*    deg  = (int*)(istd + 128);                 // 4*M int
    int*  rowptr = deg + (size_t)4 * M;                // M+1 int
    int*  cursor = rowptr + (M + 1);                   // M int
    int*  colidx = cursor + M;                         // E int
    int* partials = colidx + E;                        // 128 int
    int* blockoff = partials + 128;                    // 128 int

    int* do1 = deg;
    int* di1 = deg + M;
    int* do2 = deg + 2 * M;
    int* di2 = deg + 3 * M;

    const int BLK = 256;
    const int gemm_blocks = (M + 31) / 32;
    const int P = (M + SCAN_CHUNK - 1) / SCAN_CHUNK;   // 98 scan blocks

    // degrees (both graphs)
    hipMemsetAsync(deg, 0, (size_t)4 * M * sizeof(int), stream);
    degree_kernel<<<(E + BLK - 1) / BLK, BLK, 0, stream>>>(
        src1, dst1, src2, dst2, do1, di1, do2, di2, E);

    for (int g = 0; g < 2; ++g) {
        const float* feat = g == 0 ? feat1 : feat2;
        const int* src = g == 0 ? src1 : src2;
        const int* dst = g == 0 ? dst1 : dst2;
        const int* dgo = g == 0 ? do1 : do2;
        const int* dgi = g == 0 ? di1 : di2;
        float* Zg = out + (size_t)g * M * 128;

        // ---- build CSR by destination for graph g ----
        scan_block_sums<<<P, BLK, 0, stream>>>(dgi, partials, M);
        scan_partials<<<1, BLK, 0, stream>>>(partials, blockoff, P);
        scan_write<<<P, BLK, 0, stream>>>(dgi, blockoff, rowptr, M);
        copy_int<<<(M + BLK - 1) / BLK, BLK, 0, stream>>>(rowptr, cursor, M);
        csr_fill<<<(E + BLK - 1) / BLK, BLK, 0, stream>>>(src, dst, cursor, colidx, E);

        // ---- layer 1: Y = (feat * rs_out) @ W1 ; AGG = A @ Y ----
        gemm128_pre<<<gemm_blocks, BLK, 0, stream>>>(feat, W1, dgo, nullptr, nullptr, Y, M, 0);
        gather_spmm<<<(M * 32 + BLK - 1) / BLK, BLK, 0, stream>>>(
            (const float4*)Y, rowptr, colidx, (float4*)AGG, M);

        // ---- layer 2: Y = (relu(AGG*rs_in + b1) * rs_out) @ W2 ; AGG = A @ Y ----
        gemm128_pre<<<gemm_blocks, BLK, 0, stream>>>(AGG, W2, dgo, dgi, b1, Y, M, 1);
        gather_spmm<<<(M * 32 + BLK - 1) / BLK, BLK, 0, stream>>>(
            (const float4*)Y, rowptr, colidx, (float4*)AGG, M);

        // ---- finalize + z-score ----
        hipMemsetAsync(gsum, 0, 2 * 128 * sizeof(double), stream);
        finalize_stats<<<512, BLK, 0, stream>>>(AGG, dgi, b2, Zg, gsum, gsq, M);
        meanstd_kernel<<<1, 128, 0, stream>>>(gsum, gsq, M, mean, istd);
        normalize_kernel<<<(M * 32 + BLK - 1) / BLK, BLK, 0, stream>>>(Zg, mean, istd, M * 32);
    }
}

// Round 3
// 767.625 us; speedup vs baseline: 7.9525x; 1.3402x over previous
//
#include <hip/hip_runtime.h>
#include <cstdint>
#include <cstddef>

// ---------------------------------------------------------------------------
// CCA-SSG forward: 2-layer GraphConv (norm='both') x 2 graphs + column z-score
// Round 3: dense GEMMs -> bf16 MFMA (16x16x32), Y stored bf16 (halves gather
// traffic). CSR gather SpMM unchanged otherwise. AGG/stats stay f32/f64.
// ---------------------------------------------------------------------------

#define SCAN_CHUNK 1024

typedef __attribute__((ext_vector_type(8))) short bf16x8;   // 8 bf16 (4 VGPRs)
typedef __attribute__((ext_vector_type(4))) float f32x4;

__device__ __forceinline__ unsigned short f2bf(float f) {
    unsigned int u = __float_as_uint(f);
    unsigned int r = (u + 0x7FFFu + ((u >> 16) & 1u)) >> 16;   // RNE
    return (unsigned short)r;
}
__device__ __forceinline__ float bflo(unsigned int u) { return __uint_as_float(u << 16); }
__device__ __forceinline__ float bfhi(unsigned int u) { return __uint_as_float(u & 0xffff0000u); }

// ---- degree computation (both graphs in one pass) -------------------------
__global__ void degree_kernel(const int* __restrict__ src1, const int* __restrict__ dst1,
                              const int* __restrict__ src2, const int* __restrict__ dst2,
                              int* __restrict__ do1, int* __restrict__ di1,
                              int* __restrict__ do2, int* __restrict__ di2, int E)
{
    int t = blockIdx.x * blockDim.x + threadIdx.x;
    if (t >= E) return;
    atomicAdd(&do1[src1[t]], 1);
    atomicAdd(&di1[dst1[t]], 1);
    atomicAdd(&do2[src2[t]], 1);
    atomicAdd(&di2[dst2[t]], 1);
}

// ---- hierarchical exclusive scan of deg -> rowptr -------------------------
__global__ void scan_block_sums(const int* __restrict__ deg, int* __restrict__ partials, int M)
{
    __shared__ int sd[256];
    int base = blockIdx.x * SCAN_CHUNK + threadIdx.x * 4;
    int s = 0;
#pragma unroll
    for (int j = 0; j < 4; ++j) { int i = base + j; if (i < M) s += deg[i]; }
    sd[threadIdx.x] = s;
    __syncthreads();
    for (int off = 128; off > 0; off >>= 1) {
        if (threadIdx.x < off) sd[threadIdx.x] += sd[threadIdx.x + off];
        __syncthreads();
    }
    if (threadIdx.x == 0) partials[blockIdx.x] = sd[0];
}

__global__ void scan_partials(const int* __restrict__ partials, int* __restrict__ blockoff, int P)
{
    __shared__ int sd[256];
    int v = threadIdx.x < P ? partials[threadIdx.x] : 0;
    sd[threadIdx.x] = v;
    __syncthreads();
    for (int off = 1; off < 256; off <<= 1) {
        int t = threadIdx.x >= off ? sd[threadIdx.x - off] : 0;
        __syncthreads();
        sd[threadIdx.x] += t;
        __syncthreads();
    }
    if (threadIdx.x < P) blockoff[threadIdx.x] = sd[threadIdx.x] - v;  // exclusive
}

__global__ void scan_write(const int* __restrict__ deg, const int* __restrict__ blockoff,
                           int* __restrict__ rowptr, int M)
{
    __shared__ int sd[256];
    int base = blockIdx.x * SCAN_CHUNK + threadIdx.x * 4;
    int d0 = 0, d1 = 0, d2 = 0, d3 = 0;
    if (base + 0 < M) d0 = deg[base + 0];
    if (base + 1 < M) d1 = deg[base + 1];
    if (base + 2 < M) d2 = deg[base + 2];
    if (base + 3 < M) d3 = deg[base + 3];
    int tot = d0 + d1 + d2 + d3;
    sd[threadIdx.x] = tot;
    __syncthreads();
    for (int off = 1; off < 256; off <<= 1) {
        int t = threadIdx.x >= off ? sd[threadIdx.x - off] : 0;
        __syncthreads();
        sd[threadIdx.x] += t;
        __syncthreads();
    }
    int texcl = sd[threadIdx.x] - tot + blockoff[blockIdx.x];
    int p0 = texcl + d0, p1 = p0 + d1, p2 = p1 + d2, p3 = p2 + d3;
    if (base + 0 < M) rowptr[base + 1] = p0;
    if (base + 1 < M) rowptr[base + 2] = p1;
    if (base + 2 < M) rowptr[base + 3] = p2;
    if (base + 3 < M) rowptr[base + 4] = p3;
    if (blockIdx.x == 0 && threadIdx.x == 0) rowptr[0] = 0;
}

__global__ void copy_int(const int* __restrict__ a, int* __restrict__ b, int n)
{
    int i = blockIdx.x * blockDim.x + threadIdx.x;
    if (i < n) b[i] = a[i];
}

__global__ void csr_fill(const int* __restrict__ src, const int* __restrict__ dst,
                         int* __restrict__ cursor, int* __restrict__ colidx, int E)
{
    int e = blockIdx.x * blockDim.x + threadIdx.x;
    if (e >= E) return;
    int pos = atomicAdd(&cursor[dst[e]], 1);
    colidx[pos] = src[e];
}

// ---- W pre-swizzle into MFMA B-fragment order (bf16) ----------------------
// Wz[((t*4+s)*64 + lane)*8 + j] = bf16(W[(s*32 + (lane>>4)*8 + j)][t*16 + (lane&15)])
__global__ void wswz_kernel(const float* __restrict__ W, unsigned short* __restrict__ Wz)
{
    int i = blockIdx.x * 256 + threadIdx.x;     // 0..16383
    int j = i & 7, l = (i >> 3) & 63, s = (i >> 9) & 3, t = i >> 11;
    int k = s * 32 + ((l >> 4) * 8) + j;
    int n = t * 16 + (l & 15);
    Wz[i] = f2bf(W[k * 128 + n]);
}

// ---- fused elementwise + bf16 MFMA GEMM: Yh = f(X) @ W --------------------
// Block: 256 thr = 4 waves; 64 rows x 128 cols; K=128 -> 128 MFMAs/block.
__global__ __launch_bounds__(256) void mfma_gemm(
    const float* __restrict__ X, const unsigned short* __restrict__ Wz,
    const int* __restrict__ deg_out, const int* __restrict__ deg_in,
    const float* __restrict__ bias, unsigned short* __restrict__ Yh,
    int M, int fuse)
{
    __shared__ __align__(16) unsigned short Abf[64 * 136];  // stride 136 = 272B (17x16B)
    const int tid  = threadIdx.x;
    const int row0 = blockIdx.x * 64;

    // stage 64x128 tile: f32 -> f(x) -> bf16 in LDS
#pragma unroll
    for (int i = 0; i < 8; ++i) {
        int idx = tid + i * 256;        // 0..2047
        int r = idx >> 5, c4 = idx & 31;
        int gr = row0 + r;
        float4 v = make_float4(0.f, 0.f, 0.f, 0.f);
        if (gr < M) {
            v = ((const float4*)X)[(size_t)gr * 32 + c4];
            if (fuse) {
                float si = rsqrtf(fmaxf((float)deg_in[gr], 1.f));
                float4 bv = ((const float4*)bias)[c4];
                v.x = fmaxf(v.x * si + bv.x, 0.f);
                v.y = fmaxf(v.y * si + bv.y, 0.f);
                v.z = fmaxf(v.z * si + bv.z, 0.f);
                v.w = fmaxf(v.w * si + bv.w, 0.f);
            }
            float so = rsqrtf(fmaxf((float)deg_out[gr], 1.f));
            v.x *= so; v.y *= so; v.z *= so; v.w *= so;
        }
        unsigned int lo = (unsigned int)f2bf(v.x) | ((unsigned int)f2bf(v.y) << 16);
        unsigned int hi = (unsigned int)f2bf(v.z) | ((unsigned int)f2bf(v.w) << 16);
        *(uint2*)(Abf + r * 136 + c4 * 4) = make_uint2(lo, hi);
    }
    __syncthreads();

    const int w = tid >> 6, lane = tid & 63;
    const int m = lane & 15, quad = lane >> 4;

    // A fragments for this wave's 16 rows, all 4 k-steps (ds_read_b128 each)
    bf16x8 a[4];
#pragma unroll
    for (int s = 0; s < 4; ++s)
        a[s] = *(const bf16x8*)(Abf + (w * 16 + m) * 136 + s * 32 + quad * 8);

#pragma unroll
    for (int t = 0; t < 8; ++t) {
        f32x4 acc = {0.f, 0.f, 0.f, 0.f};
#pragma unroll
        for (int s = 0; s < 4; ++s) {
            bf16x8 b = *(const bf16x8*)(Wz + (((t * 4 + s) * 64 + lane) << 3));
            acc = __builtin_amdgcn_mfma_f32_16x16x32_bf16(a[s], b, acc, 0, 0, 0);
        }
        int gr  = row0 + w * 16 + quad * 4;   // D: row = quad*4+reg, col = lane&15
        int col = t * 16 + m;
#pragma unroll
        for (int r = 0; r < 4; ++r) {
            if (gr + r < M) Yh[(size_t)(gr + r) * 128 + col] = f2bf(acc[r]);
        }
    }
}

// ---- gather SpMM (bf16 Y): AGG[d][:] = sum_{e in row d} Y[col[e]][:] ------
// 32 lanes/node, uint2 (4 bf16) per lane, f32 register accumulation.
__global__ __launch_bounds__(256) void gather_spmm(
    const uint2* __restrict__ Yv, const int* __restrict__ rowptr,
    const int* __restrict__ colidx, float4* __restrict__ AGGv, int M)
{
    int t = blockIdx.x * blockDim.x + threadIdx.x;
    int node = t >> 5, lane = t & 31;
    if (node >= M) return;
    int e   = rowptr[node];
    int end = rowptr[node + 1];
    float ax = 0.f, ay = 0.f, az = 0.f, aw = 0.f;
    for (; e + 4 <= end; e += 4) {
        int s0 = colidx[e], s1 = colidx[e + 1], s2 = colidx[e + 2], s3 = colidx[e + 3];
        uint2 v0 = Yv[(size_t)s0 * 32 + lane];
        uint2 v1 = Yv[(size_t)s1 * 32 + lane];
        uint2 v2 = Yv[(size_t)s2 * 32 + lane];
        uint2 v3 = Yv[(size_t)s3 * 32 + lane];
        ax += bflo(v0.x) + bflo(v1.x) + bflo(v2.x) + bflo(v3.x);
        ay += bfhi(v0.x) + bfhi(v1.x) + bfhi(v2.x) + bfhi(v3.x);
        az += bflo(v0.y) + bflo(v1.y) + bflo(v2.y) + bflo(v3.y);
        aw += bfhi(v0.y) + bfhi(v1.y) + bfhi(v2.y) + bfhi(v3.y);
    }
    for (; e < end; ++e) {
        int s = colidx[e];
        uint2 v = Yv[(size_t)s * 32 + lane];
        ax += bflo(v.x); ay += bfhi(v.x); az += bflo(v.y); aw += bfhi(v.y);
    }
    AGGv[(size_t)node * 32 + lane] = make_float4(ax, ay, az, aw);
}

// ---- finalize layer 2 + column sum/sumsq ----------------------------------
__global__ __launch_bounds__(256) void finalize_stats(
    const float* __restrict__ AGG, const int* __restrict__ deg_in,
    const float* __restrict__ bias, float* __restrict__ Z,
    double* __restrict__ gsum, double* __restrict__ gsumsq, int M)
{
    const int c  = threadIdx.x & 127;
    const int rh = threadIdx.x >> 7;
    const float b = bias[c];
    float s = 0.f, s2 = 0.f;
    for (int row = blockIdx.x * 2 + rh; row < M; row += gridDim.x * 2) {
        float si = rsqrtf(fmaxf((float)deg_in[row], 1.f));
        float h = AGG[(size_t)row * 128 + c] * si + b;
        Z[(size_t)row * 128 + c] = h;
        s += h;
        s2 += h * h;
    }
    __shared__ float ls[256], ls2[256];
    ls[threadIdx.x] = s;
    ls2[threadIdx.x] = s2;
    __syncthreads();
    if (threadIdx.x < 128) {
        atomicAdd(&gsum[c],   (double)(ls[c] + ls[c + 128]));
        atomicAdd(&gsumsq[c], (double)(ls2[c] + ls2[c + 128]));
    }
}

__global__ void meanstd_kernel(const double* __restrict__ gsum,
                               const double* __restrict__ gsumsq, int M,
                               float* __restrict__ mean, float* __restrict__ istd)
{
    int c = threadIdx.x;
    double mu  = gsum[c] / (double)M;
    double var = (gsumsq[c] - gsum[c] * mu) / (double)(M - 1);
    mean[c] = (float)mu;
    istd[c] = (float)(1.0 / sqrt(var));
}

__global__ __launch_bounds__(256) void normalize_kernel(
    float* __restrict__ Z, const float* __restrict__ mean,
    const float* __restrict__ istd, int n4)
{
    int i = blockIdx.x * blockDim.x + threadIdx.x;
    if (i >= n4) return;
    float4 v = ((float4*)Z)[i];
    int c4 = (i & 31) << 2;
    v.x = (v.x - mean[c4 + 0]) * istd[c4 + 0];
    v.y = (v.y - mean[c4 + 1]) * istd[c4 + 1];
    v.z = (v.z - mean[c4 + 2]) * istd[c4 + 2];
    v.w = (v.w - mean[c4 + 3]) * istd[c4 + 3];
    ((float4*)Z)[i] = v;
}

// ---------------------------------------------------------------------------
extern "C" void kernel_launch(void* const* d_in, const int* in_sizes, int n_in,
                              void* d_out, int out_size, void* d_ws, size_t ws_size,
                              hipStream_t stream)
{
    const float* feat1 = (const float*)d_in[0];
    const float* feat2 = (const float*)d_in[1];
    const float* W1    = (const float*)d_in[2];
    const float* b1    = (const float*)d_in[3];
    const float* W2    = (const float*)d_in[4];
    const float* b2    = (const float*)d_in[5];
    const int*   src1  = (const int*)d_in[6];
    const int*   dst1  = (const int*)d_in[7];
    const int*   src2  = (const int*)d_in[8];
    const int*   dst2  = (const int*)d_in[9];
    float* out = (float*)d_out;

    const int M = in_sizes[0] / 128;   // 100000
    const int E = in_sizes[6];         // 800000

    // workspace carve-up (8B-aligned doubles first)
    double* gsum = (double*)d_ws;                                   // 128
    double* gsq  = gsum + 128;                                      // 128
    float*  AGG  = (float*)(gsq + 128);                             // M*128 f32
    unsigned short* Yh = (unsigned short*)(AGG + (size_t)M * 128);  // M*128 bf16
    unsigned short* Wz = Yh + (size_t)M * 128;                      // 2*16384 bf16 (16B-aligned)
    float*  mean = (float*)(Wz + 32768);                            // 128
    float*  istd = mean + 128;                                      // 128
    int*    deg  = (int*)(istd + 128);                              // 4*M
    int*  rowptr = deg + (size_t)4 * M;                             // M+1
    int*  cursor = rowptr + (M + 1);                                // M
    int*  colidx = cursor + M;                                      // E
    int* partials = colidx + E;                                     // 128
    int* blockoff = partials + 128;                                 // 128

    int* do1 = deg;
    int* di1 = deg + M;
    int* do2 = deg + 2 * M;
    int* di2 = deg + 3 * M;
    unsigned short* Wz1 = Wz;
    unsigned short* Wz2 = Wz + 16384;

    const int BLK = 256;
    const int gemm_blocks = (M + 63) / 64;
    const int P = (M + SCAN_CHUNK - 1) / SCAN_CHUNK;

    // degrees (both graphs) + weight swizzle (once)
    hipMemsetAsync(deg, 0, (size_t)4 * M * sizeof(int), stream);
    degree_kernel<<<(E + BLK - 1) / BLK, BLK, 0, stream>>>(
        src1, dst1, src2, dst2, do1, di1, do2, di2, E);
    wswz_kernel<<<64, BLK, 0, stream>>>(W1, Wz1);
    wswz_kernel<<<64, BLK, 0, stream>>>(W2, Wz2);

    for (int g = 0; g < 2; ++g) {
        const float* feat = g == 0 ? feat1 : feat2;
        const int* src = g == 0 ? src1 : src2;
        const int* dst = g == 0 ? dst1 : dst2;
        const int* dgo = g == 0 ? do1 : do2;
        const int* dgi = g == 0 ? di1 : di2;
        float* Zg = out + (size_t)g * M * 128;

        // ---- build CSR by destination ----
        scan_block_sums<<<P, BLK, 0, stream>>>(dgi, partials, M);
        scan_partials<<<1, BLK, 0, stream>>>(partials, blockoff, P);
        scan_write<<<P, BLK, 0, stream>>>(dgi, blockoff, rowptr, M);
        copy_int<<<(M + BLK - 1) / BLK, BLK, 0, stream>>>(rowptr, cursor, M);
        csr_fill<<<(E + BLK - 1) / BLK, BLK, 0, stream>>>(src, dst, cursor, colidx, E);

        // ---- layer 1 ----
        mfma_gemm<<<gemm_blocks, BLK, 0, stream>>>(feat, Wz1, dgo, nullptr, nullptr, Yh, M, 0);
        gather_spmm<<<(M * 32 + BLK - 1) / BLK, BLK, 0, stream>>>(
            (const uint2*)Yh, rowptr, colidx, (float4*)AGG, M);

        // ---- layer 2 ----
        mfma_gemm<<<gemm_blocks, BLK, 0, stream>>>(AGG, Wz2, dgo, dgi, b1, Yh, M, 1);
        gather_spmm<<<(M * 32 + BLK - 1) / BLK, BLK, 0, stream>>>(
            (const uint2*)Yh, rowptr, colidx, (float4*)AGG, M);

        // ---- finalize + z-score ----
        hipMemsetAsync(gsum, 0, 2 * 128 * sizeof(double), stream);
        finalize_stats<<<512, BLK, 0, stream>>>(AGG, dgi, b2, Zg, gsum, gsq, M);
        meanstd_kernel<<<1, 128, 0, stream>>>(gsum, gsq, M, mean, istd);
        normalize_kernel<<<(M * 32 + BLK - 1) / BLK, BLK, 0, stream>>>(Zg, mean, istd, M * 32);
    }
}

// Round 4
// 726.025 us; speedup vs baseline: 8.4082x; 1.0573x over previous
//
#include <hip/hip_runtime.h>
#include <cstdint>
#include <cstddef>

// ---------------------------------------------------------------------------
// CCA-SSG forward: 2-layer GraphConv (norm='both') x 2 graphs + column z-score
// Round 4: degree histograms via LDS-privatized binned counting (no global
// atomics; partials reuse AGG scratch). copy_int folded into scan_write.
// ---------------------------------------------------------------------------

#define SCAN_CHUNK 1024
#define HCHUNK 20000       // nodes per histogram chunk (80 KB LDS -> 2 blk/CU)
#define HSLICES 16         // edge slices per (array, chunk)

typedef __attribute__((ext_vector_type(8))) short bf16x8;
typedef __attribute__((ext_vector_type(4))) float f32x4;

__device__ __forceinline__ unsigned short f2bf(float f) {
    unsigned int u = __float_as_uint(f);
    unsigned int r = (u + 0x7FFFu + ((u >> 16) & 1u)) >> 16;   // RNE
    return (unsigned short)r;
}
__device__ __forceinline__ float bflo(unsigned int u) { return __uint_as_float(u << 16); }
__device__ __forceinline__ float bfhi(unsigned int u) { return __uint_as_float(u & 0xffff0000u); }

// ---- binned degree histogram: no global atomics ---------------------------
// block = (array a, chunk c, slice s). LDS histogram over HCHUNK nodes,
// coalesced non-atomic partial writeback; reduce kernel sums slices.
__global__ __launch_bounds__(256) void hist_kernel(
    const int* __restrict__ src1, const int* __restrict__ dst1,
    const int* __restrict__ src2, const int* __restrict__ dst2,
    int* __restrict__ part, int E, int nchunks)
{
    __shared__ int h[HCHUNK];
    const int bid = blockIdx.x;
    const int a = bid / (nchunks * HSLICES);
    const int r = bid % (nchunks * HSLICES);
    const int c = r / HSLICES, s = r % HSLICES;
    const int* idx = a == 0 ? src1 : a == 1 ? dst1 : a == 2 ? src2 : dst2;

    for (int i = threadIdx.x; i < HCHUNK; i += 256) h[i] = 0;
    __syncthreads();

    const int base = c * HCHUNK;
    const int lo = (int)((long long)s * E / HSLICES);
    const int hi = (int)((long long)(s + 1) * E / HSLICES);
    for (int i = lo + threadIdx.x; i < hi; i += 256) {
        unsigned int v = (unsigned int)(idx[i] - base);
        if (v < HCHUNK) atomicAdd(&h[v], 1);
    }
    __syncthreads();

    int* out = part + (size_t)bid * HCHUNK;
    for (int i = threadIdx.x; i < HCHUNK; i += 256) out[i] = h[i];
}

__global__ __launch_bounds__(256) void hist_reduce(
    const int* __restrict__ part, int* __restrict__ deg, int M, int nchunks)
{
    int i = blockIdx.x * blockDim.x + threadIdx.x;       // (a, c, n)
    int n = i % HCHUNK;
    int ac = i / HCHUNK;
    int c = ac % nchunks, a = ac / nchunks;
    if (a >= 4) return;
    int node = c * HCHUNK + n;
    if (node >= M) return;
    const int* p = part + ((size_t)(a * nchunks + c) * HSLICES) * HCHUNK + n;
    int sum = 0;
#pragma unroll
    for (int s = 0; s < HSLICES; ++s) sum += p[(size_t)s * HCHUNK];
    deg[(size_t)a * M + node] = sum;
}

// ---- hierarchical exclusive scan of deg -> rowptr (+ cursor) --------------
__global__ void scan_block_sums(const int* __restrict__ deg, int* __restrict__ partials, int M)
{
    __shared__ int sd[256];
    int base = blockIdx.x * SCAN_CHUNK + threadIdx.x * 4;
    int s = 0;
#pragma unroll
    for (int j = 0; j < 4; ++j) { int i = base + j; if (i < M) s += deg[i]; }
    sd[threadIdx.x] = s;
    __syncthreads();
    for (int off = 128; off > 0; off >>= 1) {
        if (threadIdx.x < off) sd[threadIdx.x] += sd[threadIdx.x + off];
        __syncthreads();
    }
    if (threadIdx.x == 0) partials[blockIdx.x] = sd[0];
}

__global__ void scan_partials(const int* __restrict__ partials, int* __restrict__ blockoff, int P)
{
    __shared__ int sd[256];
    int v = threadIdx.x < P ? partials[threadIdx.x] : 0;
    sd[threadIdx.x] = v;
    __syncthreads();
    for (int off = 1; off < 256; off <<= 1) {
        int t = threadIdx.x >= off ? sd[threadIdx.x - off] : 0;
        __syncthreads();
        sd[threadIdx.x] += t;
        __syncthreads();
    }
    if (threadIdx.x < P) blockoff[threadIdx.x] = sd[threadIdx.x] - v;  // exclusive
}

__global__ void scan_write(const int* __restrict__ deg, const int* __restrict__ blockoff,
                           int* __restrict__ rowptr, int* __restrict__ cursor, int M)
{
    __shared__ int sd[256];
    int base = blockIdx.x * SCAN_CHUNK + threadIdx.x * 4;
    int d0 = 0, d1 = 0, d2 = 0, d3 = 0;
    if (base + 0 < M) d0 = deg[base + 0];
    if (base + 1 < M) d1 = deg[base + 1];
    if (base + 2 < M) d2 = deg[base + 2];
    if (base + 3 < M) d3 = deg[base + 3];
    int tot = d0 + d1 + d2 + d3;
    sd[threadIdx.x] = tot;
    __syncthreads();
    for (int off = 1; off < 256; off <<= 1) {
        int t = threadIdx.x >= off ? sd[threadIdx.x - off] : 0;
        __syncthreads();
        sd[threadIdx.x] += t;
        __syncthreads();
    }
    int texcl = sd[threadIdx.x] - tot + blockoff[blockIdx.x];
    int p0 = texcl + d0, p1 = p0 + d1, p2 = p1 + d2, p3 = p2 + d3;
    if (base + 0 < M) { rowptr[base + 1] = p0; cursor[base + 0] = texcl; }
    if (base + 1 < M) { rowptr[base + 2] = p1; cursor[base + 1] = p0; }
    if (base + 2 < M) { rowptr[base + 3] = p2; cursor[base + 2] = p1; }
    if (base + 3 < M) { rowptr[base + 4] = p3; cursor[base + 3] = p2; }
    if (blockIdx.x == 0 && threadIdx.x == 0) rowptr[0] = 0;
}

__global__ void csr_fill(const int* __restrict__ src, const int* __restrict__ dst,
                         int* __restrict__ cursor, int* __restrict__ colidx, int E)
{
    int e = blockIdx.x * blockDim.x + threadIdx.x;
    if (e >= E) return;
    int pos = atomicAdd(&cursor[dst[e]], 1);
    colidx[pos] = src[e];
}

// ---- W pre-swizzle into MFMA B-fragment order (bf16) ----------------------
__global__ void wswz_kernel(const float* __restrict__ W, unsigned short* __restrict__ Wz)
{
    int i = blockIdx.x * 256 + threadIdx.x;     // 0..16383
    int j = i & 7, l = (i >> 3) & 63, s = (i >> 9) & 3, t = i >> 11;
    int k = s * 32 + ((l >> 4) * 8) + j;
    int n = t * 16 + (l & 15);
    Wz[i] = f2bf(W[k * 128 + n]);
}

// ---- fused elementwise + bf16 MFMA GEMM: Yh = f(X) @ W --------------------
__global__ __launch_bounds__(256) void mfma_gemm(
    const float* __restrict__ X, const unsigned short* __restrict__ Wz,
    const int* __restrict__ deg_out, const int* __restrict__ deg_in,
    const float* __restrict__ bias, unsigned short* __restrict__ Yh,
    int M, int fuse)
{
    __shared__ __align__(16) unsigned short Abf[64 * 136];
    const int tid  = threadIdx.x;
    const int row0 = blockIdx.x * 64;

#pragma unroll
    for (int i = 0; i < 8; ++i) {
        int idx = tid + i * 256;
        int r = idx >> 5, c4 = idx & 31;
        int gr = row0 + r;
        float4 v = make_float4(0.f, 0.f, 0.f, 0.f);
        if (gr < M) {
            v = ((const float4*)X)[(size_t)gr * 32 + c4];
            if (fuse) {
                float si = rsqrtf(fmaxf((float)deg_in[gr], 1.f));
                float4 bv = ((const float4*)bias)[c4];
                v.x = fmaxf(v.x * si + bv.x, 0.f);
                v.y = fmaxf(v.y * si + bv.y, 0.f);
                v.z = fmaxf(v.z * si + bv.z, 0.f);
                v.w = fmaxf(v.w * si + bv.w, 0.f);
            }
            float so = rsqrtf(fmaxf((float)deg_out[gr], 1.f));
            v.x *= so; v.y *= so; v.z *= so; v.w *= so;
        }
        unsigned int lo = (unsigned int)f2bf(v.x) | ((unsigned int)f2bf(v.y) << 16);
        unsigned int hi = (unsigned int)f2bf(v.z) | ((unsigned int)f2bf(v.w) << 16);
        *(uint2*)(Abf + r * 136 + c4 * 4) = make_uint2(lo, hi);
    }
    __syncthreads();

    const int w = tid >> 6, lane = tid & 63;
    const int m = lane & 15, quad = lane >> 4;

    bf16x8 a[4];
#pragma unroll
    for (int s = 0; s < 4; ++s)
        a[s] = *(const bf16x8*)(Abf + (w * 16 + m) * 136 + s * 32 + quad * 8);

#pragma unroll
    for (int t = 0; t < 8; ++t) {
        f32x4 acc = {0.f, 0.f, 0.f, 0.f};
#pragma unroll
        for (int s = 0; s < 4; ++s) {
            bf16x8 b = *(const bf16x8*)(Wz + (((t * 4 + s) * 64 + lane) << 3));
            acc = __builtin_amdgcn_mfma_f32_16x16x32_bf16(a[s], b, acc, 0, 0, 0);
        }
        int gr  = row0 + w * 16 + quad * 4;
        int col = t * 16 + m;
#pragma unroll
        for (int r = 0; r < 4; ++r) {
            if (gr + r < M) Yh[(size_t)(gr + r) * 128 + col] = f2bf(acc[r]);
        }
    }
}

// ---- gather SpMM (bf16 Y): AGG[d][:] = sum_{e in row d} Y[col[e]][:] ------
__global__ __launch_bounds__(256) void gather_spmm(
    const uint2* __restrict__ Yv, const int* __restrict__ rowptr,
    const int* __restrict__ colidx, float4* __restrict__ AGGv, int M)
{
    int t = blockIdx.x * blockDim.x + threadIdx.x;
    int node = t >> 5, lane = t & 31;
    if (node >= M) return;
    int e   = rowptr[node];
    int end = rowptr[node + 1];
    float ax = 0.f, ay = 0.f, az = 0.f, aw = 0.f;
    for (; e + 4 <= end; e += 4) {
        int s0 = colidx[e], s1 = colidx[e + 1], s2 = colidx[e + 2], s3 = colidx[e + 3];
        uint2 v0 = Yv[(size_t)s0 * 32 + lane];
        uint2 v1 = Yv[(size_t)s1 * 32 + lane];
        uint2 v2 = Yv[(size_t)s2 * 32 + lane];
        uint2 v3 = Yv[(size_t)s3 * 32 + lane];
        ax += bflo(v0.x) + bflo(v1.x) + bflo(v2.x) + bflo(v3.x);
        ay += bfhi(v0.x) + bfhi(v1.x) + bfhi(v2.x) + bfhi(v3.x);
        az += bflo(v0.y) + bflo(v1.y) + bflo(v2.y) + bflo(v3.y);
        aw += bfhi(v0.y) + bfhi(v1.y) + bfhi(v2.y) + bfhi(v3.y);
    }
    for (; e < end; ++e) {
        int s = colidx[e];
        uint2 v = Yv[(size_t)s * 32 + lane];
        ax += bflo(v.x); ay += bfhi(v.x); az += bflo(v.y); aw += bfhi(v.y);
    }
    AGGv[(size_t)node * 32 + lane] = make_float4(ax, ay, az, aw);
}

// ---- finalize layer 2 + column sum/sumsq ----------------------------------
__global__ __launch_bounds__(256) void finalize_stats(
    const float* __restrict__ AGG, const int* __restrict__ deg_in,
    const float* __restrict__ bias, float* __restrict__ Z,
    double* __restrict__ gsum, double* __restrict__ gsumsq, int M)
{
    const int c  = threadIdx.x & 127;
    const int rh = threadIdx.x >> 7;
    const float b = bias[c];
    float s = 0.f, s2 = 0.f;
    for (int row = blockIdx.x * 2 + rh; row < M; row += gridDim.x * 2) {
        float si = rsqrtf(fmaxf((float)deg_in[row], 1.f));
        float h = AGG[(size_t)row * 128 + c] * si + b;
        Z[(size_t)row * 128 + c] = h;
        s += h;
        s2 += h * h;
    }
    __shared__ float ls[256], ls2[256];
    ls[threadIdx.x] = s;
    ls2[threadIdx.x] = s2;
    __syncthreads();
    if (threadIdx.x < 128) {
        atomicAdd(&gsum[c],   (double)(ls[c] + ls[c + 128]));
        atomicAdd(&gsumsq[c], (double)(ls2[c] + ls2[c + 128]));
    }
}

__global__ void meanstd_kernel(const double* __restrict__ gsum,
                               const double* __restrict__ gsumsq, int M,
                               float* __restrict__ mean, float* __restrict__ istd)
{
    int c = threadIdx.x;
    double mu  = gsum[c] / (double)M;
    double var = (gsumsq[c] - gsum[c] * mu) / (double)(M - 1);
    mean[c] = (float)mu;
    istd[c] = (float)(1.0 / sqrt(var));
}

__global__ __launch_bounds__(256) void normalize_kernel(
    float* __restrict__ Z, const float* __restrict__ mean,
    const float* __restrict__ istd, int n4)
{
    int i = blockIdx.x * blockDim.x + threadIdx.x;
    if (i >= n4) return;
    float4 v = ((float4*)Z)[i];
    int c4 = (i & 31) << 2;
    v.x = (v.x - mean[c4 + 0]) * istd[c4 + 0];
    v.y = (v.y - mean[c4 + 1]) * istd[c4 + 1];
    v.z = (v.z - mean[c4 + 2]) * istd[c4 + 2];
    v.w = (v.w - mean[c4 + 3]) * istd[c4 + 3];
    ((float4*)Z)[i] = v;
}

// ---------------------------------------------------------------------------
extern "C" void kernel_launch(void* const* d_in, const int* in_sizes, int n_in,
                              void* d_out, int out_size, void* d_ws, size_t ws_size,
                              hipStream_t stream)
{
    const float* feat1 = (const float*)d_in[0];
    const float* feat2 = (const float*)d_in[1];
    const float* W1    = (const float*)d_in[2];
    const float* b1    = (const float*)d_in[3];
    const float* W2    = (const float*)d_in[4];
    const float* b2    = (const float*)d_in[5];
    const int*   src1  = (const int*)d_in[6];
    const int*   dst1  = (const int*)d_in[7];
    const int*   src2  = (const int*)d_in[8];
    const int*   dst2  = (const int*)d_in[9];
    float* out = (float*)d_out;

    const int M = in_sizes[0] / 128;   // 100000
    const int E = in_sizes[6];         // 800000

    // workspace carve-up
    double* gsum = (double*)d_ws;                                   // 128
    double* gsq  = gsum + 128;                                      // 128
    float*  AGG  = (float*)(gsq + 128);                             // M*128 f32
    unsigned short* Yh = (unsigned short*)(AGG + (size_t)M * 128);  // M*128 bf16
    unsigned short* Wz = Yh + (size_t)M * 128;                      // 2*16384 bf16
    float*  mean = (float*)(Wz + 32768);                            // 128
    float*  istd = mean + 128;                                      // 128
    int*    deg  = (int*)(istd + 128);                              // 4*M
    int*  rowptr = deg + (size_t)4 * M;                             // M+1
    int*  cursor = rowptr + (M + 1);                                // M
    int*  colidx = cursor + M;                                      // E
    int* spart   = colidx + E;                                      // 256
    int* blockoff = spart + 256;                                    // 256

    int* do1 = deg;
    int* di1 = deg + M;
    int* do2 = deg + 2 * M;
    int* di2 = deg + 3 * M;
    unsigned short* Wz1 = Wz;
    unsigned short* Wz2 = Wz + 16384;

    // histogram partials reuse AGG scratch (AGG first written much later)
    int* hpart = (int*)AGG;   // 4*nchunks*HSLICES*HCHUNK ints = 25.6 MB < 51.2 MB

    const int BLK = 256;
    const int gemm_blocks = (M + 63) / 64;
    const int P = (M + SCAN_CHUNK - 1) / SCAN_CHUNK;
    const int nchunks = (M + HCHUNK - 1) / HCHUNK;      // 5
    const int hist_blocks = 4 * nchunks * HSLICES;      // 320
    const int hr_total = 4 * nchunks * HCHUNK;          // 400000

    // degrees (no global atomics) + weight swizzle
    hist_kernel<<<hist_blocks, BLK, 0, stream>>>(src1, dst1, src2, dst2, hpart, E, nchunks);
    hist_reduce<<<(hr_total + BLK - 1) / BLK, BLK, 0, stream>>>(hpart, deg, M, nchunks);
    wswz_kernel<<<64, BLK, 0, stream>>>(W1, Wz1);
    wswz_kernel<<<64, BLK, 0, stream>>>(W2, Wz2);

    for (int g = 0; g < 2; ++g) {
        const float* feat = g == 0 ? feat1 : feat2;
        const int* src = g == 0 ? src1 : src2;
        const int* dst = g == 0 ? dst1 : dst2;
        const int* dgo = g == 0 ? do1 : do2;
        const int* dgi = g == 0 ? di1 : di2;
        float* Zg = out + (size_t)g * M * 128;

        // ---- build CSR by destination ----
        scan_block_sums<<<P, BLK, 0, stream>>>(dgi, spart, M);
        scan_partials<<<1, BLK, 0, stream>>>(spart, blockoff, P);
        scan_write<<<P, BLK, 0, stream>>>(dgi, blockoff, rowptr, cursor, M);
        csr_fill<<<(E + BLK - 1) / BLK, BLK, 0, stream>>>(src, dst, cursor, colidx, E);

        // ---- layer 1 ----
        mfma_gemm<<<gemm_blocks, BLK, 0, stream>>>(feat, Wz1, dgo, nullptr, nullptr, Yh, M, 0);
        gather_spmm<<<(M * 32 + BLK - 1) / BLK, BLK, 0, stream>>>(
            (const uint2*)Yh, rowptr, colidx, (float4*)AGG, M);

        // ---- layer 2 ----
        mfma_gemm<<<gemm_blocks, BLK, 0, stream>>>(AGG, Wz2, dgo, dgi, b1, Yh, M, 1);
        gather_spmm<<<(M * 32 + BLK - 1) / BLK, BLK, 0, stream>>>(
            (const uint2*)Yh, rowptr, colidx, (float4*)AGG, M);

        // ---- finalize + z-score ----
        hipMemsetAsync(gsum, 0, 2 * 128 * sizeof(double), stream);
        finalize_stats<<<512, BLK, 0, stream>>>(AGG, dgi, b2, Zg, gsum, gsq, M);
        meanstd_kernel<<<1, 128, 0, stream>>>(gsum, gsq, M, mean, istd);
        normalize_kernel<<<(M * 32 + BLK - 1) / BLK, BLK, 0, stream>>>(Zg, mean, istd, M * 32);
    }
}